// Round 1
// baseline (580.271 us; speedup 1.0000x reference)
//
#include <hip/hip_runtime.h>

#define T_SEQ   2048
#define NHEADS  12
#define DHEAD   64
#define WIN     16
#define WW      32
#define NWIN    128
#define DMODEL  768
#define NABCDE  3840
#define IGNORE_V (-1.0e6f)

// ---------------------------------------------------------------------------
// fp32 GEMM with bias: C[M,N] = A[M,K] @ B[K,N] + bias[N]
// 128x128 tile, BK=16, 256 threads, 8x8 micro-tile. All dims assumed
// multiples of tile sizes (true here: M=4096, N in {3840,768}, K=768).
// ---------------------------------------------------------------------------
__global__ __launch_bounds__(256) void gemm_bias_kernel(
    const float* __restrict__ A, const float* __restrict__ B,
    const float* __restrict__ bias, float* __restrict__ C,
    int M, int N, int K)
{
    __shared__ float As[16][128];   // transposed A tile: As[k][m]
    __shared__ float Bs[16][128];   // Bs[k][n]
    const int tid = threadIdx.x;
    const int bm = blockIdx.y * 128;
    const int bn = blockIdx.x * 128;
    const int ty = tid >> 4, tx = tid & 15;
    const int m0 = ty * 8, n0 = tx * 8;

    float acc[8][8];
#pragma unroll
    for (int i = 0; i < 8; ++i)
#pragma unroll
        for (int j = 0; j < 8; ++j) acc[i][j] = 0.f;

    for (int k0 = 0; k0 < K; k0 += 16) {
        // A tile: 128 rows x 16 cols = 512 float4, 2 per thread
#pragma unroll
        for (int r = 0; r < 2; ++r) {
            int f = tid + r * 256;
            int row = f >> 2;
            int c4 = (f & 3) << 2;
            float4 v = *reinterpret_cast<const float4*>(
                &A[(size_t)(bm + row) * K + k0 + c4]);
            As[c4 + 0][row] = v.x;
            As[c4 + 1][row] = v.y;
            As[c4 + 2][row] = v.z;
            As[c4 + 3][row] = v.w;
        }
        // B tile: 16 rows x 128 cols = 512 float4, 2 per thread
#pragma unroll
        for (int r = 0; r < 2; ++r) {
            int f = tid + r * 256;
            int row = f >> 5;
            int c4 = (f & 31) << 2;
            *reinterpret_cast<float4*>(&Bs[row][c4]) =
                *reinterpret_cast<const float4*>(
                    &B[(size_t)(k0 + row) * N + bn + c4]);
        }
        __syncthreads();
#pragma unroll
        for (int k = 0; k < 16; ++k) {
            float4 a0 = *reinterpret_cast<const float4*>(&As[k][m0]);
            float4 a1 = *reinterpret_cast<const float4*>(&As[k][m0 + 4]);
            float4 b0 = *reinterpret_cast<const float4*>(&Bs[k][n0]);
            float4 b1 = *reinterpret_cast<const float4*>(&Bs[k][n0 + 4]);
            float ra[8] = {a0.x, a0.y, a0.z, a0.w, a1.x, a1.y, a1.z, a1.w};
            float rb[8] = {b0.x, b0.y, b0.z, b0.w, b1.x, b1.y, b1.z, b1.w};
#pragma unroll
            for (int i = 0; i < 8; ++i)
#pragma unroll
                for (int j = 0; j < 8; ++j)
                    acc[i][j] = fmaf(ra[i], rb[j], acc[i][j]);
        }
        __syncthreads();
    }
#pragma unroll
    for (int i = 0; i < 8; ++i) {
#pragma unroll
        for (int j = 0; j < 8; j += 4) {
            float4 v;
            v.x = acc[i][j + 0] + bias[bn + n0 + j + 0];
            v.y = acc[i][j + 1] + bias[bn + n0 + j + 1];
            v.z = acc[i][j + 2] + bias[bn + n0 + j + 2];
            v.w = acc[i][j + 3] + bias[bn + n0 + j + 3];
            *reinterpret_cast<float4*>(
                &C[(size_t)(bm + m0 + i) * N + bn + n0 + j]) = v;
        }
    }
}

// ---------------------------------------------------------------------------
// Windowed trittention. One block per (bh, window): grid = 24*128 = 3072.
// 256 threads = 4 waves; wave g handles queries i = g*4..g*4+3; within a
// wave, lane s owns a 4x4 (m,l) sub-tile: m0=(s&7)*4, l0=(s>>3)*4.
// scores[i,m,l] = sum_d c[i,d]*a_l[m,d]*b_l[l,d]  (kept in 64 regs/lane)
// Then mask + score==0->IGNORE + softmax over the 1024 (m,l) entries
// (wave-wide shuffle reduce), marginals pm[i,m]=sum_l, pl[i,l]=sum_m via
// partial shuffle reductions, and z = pm@d_l + pl@e_l.
// ---------------------------------------------------------------------------
__global__ __launch_bounds__(256) void attn_kernel(
    const float* __restrict__ abcde, float* __restrict__ z)
{
    const int blk = blockIdx.x;
    const int n  = blk & (NWIN - 1);
    const int bh = blk >> 7;
    const int b  = bh / NHEADS;
    const int h  = bh % NHEADS;

    __shared__ float sc[WIN][DHEAD + 1];   // +1 pad: conflict-free scalar reads
    __shared__ float sa[WW][DHEAD + 1];
    __shared__ float sb[WW][DHEAD + 1];
    __shared__ float sd[WW][DHEAD];
    __shared__ float se[WW][DHEAD];
    __shared__ float pm_s[WIN][WW];
    __shared__ float pl_s[WIN][WW];

    const int tid = threadIdx.x;
    const size_t rowbase = ((size_t)b * T_SEQ) * NABCDE;
    const int hd = h * DHEAD;

    // ---- stage c (16x64) : 256 float4, 1/thread
    {
        int i  = tid >> 4;
        int d4 = (tid & 15) << 2;
        float4 v = *reinterpret_cast<const float4*>(
            &abcde[rowbase + (size_t)(n * WIN + i) * NABCDE + 2 * DMODEL + hd + d4]);
        sc[i][d4 + 0] = v.x; sc[i][d4 + 1] = v.y;
        sc[i][d4 + 2] = v.z; sc[i][d4 + 3] = v.w;
    }
    // ---- stage a,b,d,e look-around tiles (32x64 each): zero-pad window -1
#pragma unroll
    for (int r = 0; r < 2; ++r) {
        int f  = tid + r * 256;          // [0,512)
        int m  = f >> 4;                 // 0..31
        int d4 = (f & 15) << 2;
        int t  = n * WIN - WIN + m;      // absolute position for this slot
        float4 va = make_float4(0.f, 0.f, 0.f, 0.f), vb = va, vd = va, ve = va;
        if (t >= 0) {
            size_t base = rowbase + (size_t)t * NABCDE + hd + d4;
            va = *reinterpret_cast<const float4*>(&abcde[base + 0 * DMODEL]);
            vb = *reinterpret_cast<const float4*>(&abcde[base + 1 * DMODEL]);
            vd = *reinterpret_cast<const float4*>(&abcde[base + 3 * DMODEL]);
            ve = *reinterpret_cast<const float4*>(&abcde[base + 4 * DMODEL]);
        }
        sa[m][d4 + 0] = va.x; sa[m][d4 + 1] = va.y; sa[m][d4 + 2] = va.z; sa[m][d4 + 3] = va.w;
        sb[m][d4 + 0] = vb.x; sb[m][d4 + 1] = vb.y; sb[m][d4 + 2] = vb.z; sb[m][d4 + 3] = vb.w;
        *reinterpret_cast<float4*>(&sd[m][d4]) = vd;
        *reinterpret_cast<float4*>(&se[m][d4]) = ve;
    }
    __syncthreads();

    const int g  = tid >> 6;        // wave id 0..3
    const int s  = tid & 63;        // lane
    const int m0 = (s & 7) << 2;    // 0,4,...,28
    const int l0 = (s >> 3) << 2;

    float p[4][4][4];
#pragma unroll
    for (int ii = 0; ii < 4; ++ii)
#pragma unroll
        for (int mi = 0; mi < 4; ++mi)
#pragma unroll
            for (int li = 0; li < 4; ++li) p[ii][mi][li] = 0.f;

    // ---- third-order scores
#pragma unroll 4
    for (int d = 0; d < DHEAD; ++d) {
        float cv[4], av[4], bv[4];
#pragma unroll
        for (int ii = 0; ii < 4; ++ii) cv[ii] = sc[g * 4 + ii][d];
#pragma unroll
        for (int mi = 0; mi < 4; ++mi) av[mi] = sa[m0 + mi][d];
#pragma unroll
        for (int li = 0; li < 4; ++li) bv[li] = sb[l0 + li][d];
#pragma unroll
        for (int mi = 0; mi < 4; ++mi)
#pragma unroll
            for (int li = 0; li < 4; ++li) {
                float ab = av[mi] * bv[li];
#pragma unroll
                for (int ii = 0; ii < 4; ++ii)
                    p[ii][mi][li] = fmaf(cv[ii], ab, p[ii][mi][li]);
            }
    }

    // ---- mask (exact reference construction incl. pad-zero bb) + zero-hack
    const int nbase = n * WIN;
#pragma unroll
    for (int ii = 0; ii < 4; ++ii) {
        int tq = nbase + g * 4 + ii;
#pragma unroll
        for (int mi = 0; mi < 4; ++mi) {
            int m = m0 + mi;
            int bbm = (n == 0 && m < WIN) ? 0 : (nbase - WIN + m);
#pragma unroll
            for (int li = 0; li < 4; ++li) {
                int l = l0 + li;
                int bbl = (n == 0 && l < WIN) ? 0 : (nbase - WIN + l);
                float v = p[ii][mi][li];
                bool keep = (tq >= bbl) && (bbl > bbm);
                if (!keep) v = IGNORE_V;
                if (v == 0.0f) v = IGNORE_V;
                p[ii][mi][li] = v * (1.0f / 64.0f);
            }
        }
    }

    // ---- softmax per query i over all 1024 (m,l): wave-wide reduce
#pragma unroll
    for (int ii = 0; ii < 4; ++ii) {
        float mx = -3.4e38f;
#pragma unroll
        for (int mi = 0; mi < 4; ++mi)
#pragma unroll
            for (int li = 0; li < 4; ++li) mx = fmaxf(mx, p[ii][mi][li]);
#pragma unroll
        for (int off = 1; off < 64; off <<= 1)
            mx = fmaxf(mx, __shfl_xor(mx, off, 64));
        float sum = 0.f;
#pragma unroll
        for (int mi = 0; mi < 4; ++mi)
#pragma unroll
            for (int li = 0; li < 4; ++li) {
                float e = __expf(p[ii][mi][li] - mx);
                p[ii][mi][li] = e;
                sum += e;
            }
#pragma unroll
        for (int off = 1; off < 64; off <<= 1)
            sum += __shfl_xor(sum, off, 64);
        float inv = 1.0f / sum;
#pragma unroll
        for (int mi = 0; mi < 4; ++mi)
#pragma unroll
            for (int li = 0; li < 4; ++li) p[ii][mi][li] *= inv;
    }

    // ---- marginals pm[i,m] = sum_l p, pl[i,l] = sum_m p
#pragma unroll
    for (int ii = 0; ii < 4; ++ii) {
        int i = g * 4 + ii;
#pragma unroll
        for (int mi = 0; mi < 4; ++mi) {
            float pm = p[ii][mi][0] + p[ii][mi][1] + p[ii][mi][2] + p[ii][mi][3];
            pm += __shfl_xor(pm, 8, 64);
            pm += __shfl_xor(pm, 16, 64);
            pm += __shfl_xor(pm, 32, 64);
            if ((s >> 3) == 0) pm_s[i][m0 + mi] = pm;
        }
#pragma unroll
        for (int li = 0; li < 4; ++li) {
            float pl = p[ii][0][li] + p[ii][1][li] + p[ii][2][li] + p[ii][3][li];
            pl += __shfl_xor(pl, 1, 64);
            pl += __shfl_xor(pl, 2, 64);
            pl += __shfl_xor(pl, 4, 64);
            if ((s & 7) == 0) pl_s[i][l0 + li] = pl;
        }
    }
    __syncthreads();

    // ---- z[i,d] = sum_m pm[i,m]*d_l[m,d] + sum_l pl[i,l]*e_l[l,d]
    {
        int i  = tid >> 4;
        int d0 = (tid & 15) << 2;
        float4 acc = make_float4(0.f, 0.f, 0.f, 0.f);
#pragma unroll 8
        for (int m = 0; m < WW; ++m) {
            float pmv = pm_s[i][m];
            float4 dv = *reinterpret_cast<const float4*>(&sd[m][d0]);
            acc.x = fmaf(pmv, dv.x, acc.x);
            acc.y = fmaf(pmv, dv.y, acc.y);
            acc.z = fmaf(pmv, dv.z, acc.z);
            acc.w = fmaf(pmv, dv.w, acc.w);
            float plv = pl_s[i][m];
            float4 ev = *reinterpret_cast<const float4*>(&se[m][d0]);
            acc.x = fmaf(plv, ev.x, acc.x);
            acc.y = fmaf(plv, ev.y, acc.y);
            acc.z = fmaf(plv, ev.z, acc.z);
            acc.w = fmaf(plv, ev.w, acc.w);
        }
        size_t zoff = ((size_t)b * T_SEQ + n * WIN + i) * (NHEADS * DHEAD) + hd + d0;
        *reinterpret_cast<float4*>(&z[zoff]) = acc;
    }
}

// ---------------------------------------------------------------------------
extern "C" void kernel_launch(void* const* d_in, const int* in_sizes, int n_in,
                              void* d_out, int out_size, void* d_ws, size_t ws_size,
                              hipStream_t stream) {
    const float* x        = (const float*)d_in[0];
    const float* W_abcde  = (const float*)d_in[1];
    const float* b_abcde  = (const float*)d_in[2];
    const float* W_O      = (const float*)d_in[3];
    const float* b_O      = (const float*)d_in[4];
    float* out = (float*)d_out;

    float* abcde = (float*)d_ws;                        // 4096 x 3840 fp32
    float* z     = abcde + (size_t)4096 * NABCDE;       // 4096 x 768  fp32

    const int M = 2 * T_SEQ;  // 4096

    // GEMM1: abcde = x @ W_abcde + b_abcde
    gemm_bias_kernel<<<dim3(NABCDE / 128, M / 128), dim3(256), 0, stream>>>(
        x, W_abcde, b_abcde, abcde, M, NABCDE, DMODEL);

    // windowed trittention -> z (B,T,H*D)
    attn_kernel<<<dim3(2 * NHEADS * NWIN), dim3(256), 0, stream>>>(abcde, z);

    // GEMM2: out = z @ W_O + b_O
    gemm_bias_kernel<<<dim3(DMODEL / 128, M / 128), dim3(256), 0, stream>>>(
        z, W_O, b_O, out, M, DMODEL, DMODEL);
}

// Round 2
// 261.684 us; speedup vs baseline: 2.2175x; 2.2175x over previous
//
#include <hip/hip_runtime.h>

#define T_SEQ   2048
#define NHEADS  12
#define DHEAD   64
#define WIN     16
#define WW      32
#define NWIN    128
#define DMODEL  768
#define NABCDE  3840
#define IGNORE_V (-1.0e6f)

typedef float f32x4 __attribute__((ext_vector_type(4)));
typedef short bf16x8 __attribute__((ext_vector_type(8)));

__device__ __forceinline__ short f2bf(float f) {
    unsigned u = __float_as_uint(f);
    unsigned r = (u + 0x7FFF + ((u >> 16) & 1)) >> 16;   // RNE
    return (short)r;
}

__device__ __forceinline__ void gload_lds16(const short* g, short* l) {
    __builtin_amdgcn_global_load_lds(
        (const __attribute__((address_space(1))) void*)g,
        (__attribute__((address_space(3))) void*)l,
        16, 0, 0);
}

// ---------------------------------------------------------------------------
// cast fp32 -> bf16, same layout. 8 elements/thread.
// ---------------------------------------------------------------------------
__global__ __launch_bounds__(256) void cast_bf16_kernel(
    const float* __restrict__ in, short* __restrict__ out, int n)
{
    int i = (blockIdx.x * 256 + threadIdx.x) * 8;
    if (i >= n) return;
    float4 a = *reinterpret_cast<const float4*>(&in[i]);
    float4 b = *reinterpret_cast<const float4*>(&in[i + 4]);
    union { short s[8]; uint4 u; } r;
    r.s[0] = f2bf(a.x); r.s[1] = f2bf(a.y); r.s[2] = f2bf(a.z); r.s[3] = f2bf(a.w);
    r.s[4] = f2bf(b.x); r.s[5] = f2bf(b.y); r.s[6] = f2bf(b.z); r.s[7] = f2bf(b.w);
    *reinterpret_cast<uint4*>(&out[i]) = r.u;
}

// ---------------------------------------------------------------------------
// transpose + cast: W[K][N] fp32 -> Wt[N][K] bf16.  32x32 LDS tile.
// ---------------------------------------------------------------------------
__global__ __launch_bounds__(256) void transpose_cast_kernel(
    const float* __restrict__ W, short* __restrict__ Wt, int K, int N)
{
    __shared__ float tile[32][33];
    const int bx = blockIdx.x * 32;   // n base
    const int by = blockIdx.y * 32;   // k base
    const int tx = threadIdx.x & 31, ty = threadIdx.x >> 5;   // 32x8
#pragma unroll
    for (int r = 0; r < 32; r += 8)
        tile[ty + r][tx] = W[(size_t)(by + ty + r) * N + bx + tx];
    __syncthreads();
#pragma unroll
    for (int r = 0; r < 32; r += 8)
        Wt[(size_t)(bx + ty + r) * K + by + tx] = f2bf(tile[tx][ty + r]);
}

// ---------------------------------------------------------------------------
// bf16 MFMA GEMM (m97 structure): C[M,N] = A[M,K] @ Bt[N,K]^T + bias[N]
// A row-major bf16, Bt row-major bf16 (i.e. B transposed), C fp32.
// 128x128 tile, BK=32, 256 threads = 4 waves (2x2 of 64x64), 4x4 grid of
// 16x16x32 MFMAs per wave. global_load_lds width=16 staging.
// ---------------------------------------------------------------------------
__global__ __launch_bounds__(256) void gemm_bf16_mfma(
    const short* __restrict__ A, const short* __restrict__ Bt,
    const float* __restrict__ bias, float* __restrict__ C,
    int M, int N, int K)
{
    __shared__ short As[128 * 32];   // [m][k], 32 bf16 per row
    __shared__ short Bs[128 * 32];   // [n][k]

    const int tid  = threadIdx.x;
    const int wave = tid >> 6;
    const int lane = tid & 63;
    const int bm = blockIdx.y * 128;
    const int bn = blockIdx.x * 128;

    // staging: lane covers (row = base + lane>>2, kchunk = (lane&3)*8)
    const int st_row = lane >> 2;
    const int st_col = (lane & 3) * 8;

    // fragment read coords
    const int fr_m = lane & 15;
    const int fr_k = (lane >> 4) * 8;

    const int wm = (wave >> 1) * 64;
    const int wn = (wave & 1) * 64;

    f32x4 acc[4][4];
#pragma unroll
    for (int mi = 0; mi < 4; ++mi)
#pragma unroll
        for (int ni = 0; ni < 4; ++ni) acc[mi][ni] = (f32x4){0.f, 0.f, 0.f, 0.f};

    const short* Abase0 = A  + (size_t)(bm + wave * 32 + st_row)      * K + st_col;
    const short* Abase1 = A  + (size_t)(bm + wave * 32 + 16 + st_row) * K + st_col;
    const short* Bbase0 = Bt + (size_t)(bn + wave * 32 + st_row)      * K + st_col;
    const short* Bbase1 = Bt + (size_t)(bn + wave * 32 + 16 + st_row) * K + st_col;
    short* AL0 = &As[(wave * 32)      * 32];
    short* AL1 = &As[(wave * 32 + 16) * 32];
    short* BL0 = &Bs[(wave * 32)      * 32];
    short* BL1 = &Bs[(wave * 32 + 16) * 32];

    for (int k0 = 0; k0 < K; k0 += 32) {
        gload_lds16(Abase0 + k0, AL0);
        gload_lds16(Abase1 + k0, AL1);
        gload_lds16(Bbase0 + k0, BL0);
        gload_lds16(Bbase1 + k0, BL1);
        __syncthreads();   // vmcnt drain -> LDS tiles ready

        bf16x8 af[4], bf[4];
#pragma unroll
        for (int mi = 0; mi < 4; ++mi)
            af[mi] = *reinterpret_cast<const bf16x8*>(
                &As[(wm + mi * 16 + fr_m) * 32 + fr_k]);
#pragma unroll
        for (int ni = 0; ni < 4; ++ni)
            bf[ni] = *reinterpret_cast<const bf16x8*>(
                &Bs[(wn + ni * 16 + fr_m) * 32 + fr_k]);
#pragma unroll
        for (int mi = 0; mi < 4; ++mi)
#pragma unroll
            for (int ni = 0; ni < 4; ++ni)
                acc[mi][ni] = __builtin_amdgcn_mfma_f32_16x16x32_bf16(
                    af[mi], bf[ni], acc[mi][ni], 0, 0, 0);
        __syncthreads();   // all reads done before next stage overwrites
    }

    // epilogue: C/D layout col=lane&15, row=(lane>>4)*4+reg
    float bv[4];
#pragma unroll
    for (int ni = 0; ni < 4; ++ni)
        bv[ni] = bias[bn + wn + ni * 16 + (lane & 15)];
#pragma unroll
    for (int mi = 0; mi < 4; ++mi) {
        int rbase = bm + wm + mi * 16 + (lane >> 4) * 4;
#pragma unroll
        for (int r = 0; r < 4; ++r) {
            float* crow = &C[(size_t)(rbase + r) * N + bn + wn + (lane & 15)];
#pragma unroll
            for (int ni = 0; ni < 4; ++ni)
                crow[ni * 16] = acc[mi][ni][r] + bv[ni];
        }
    }
}

// ---------------------------------------------------------------------------
// Windowed trittention (unchanged except z written as bf16).
// ---------------------------------------------------------------------------
__global__ __launch_bounds__(256) void attn_kernel(
    const float* __restrict__ abcde, short* __restrict__ z)
{
    const int blk = blockIdx.x;
    const int n  = blk & (NWIN - 1);
    const int bh = blk >> 7;
    const int b  = bh / NHEADS;
    const int h  = bh % NHEADS;

    __shared__ float sc[WIN][DHEAD + 1];
    __shared__ float sa[WW][DHEAD + 1];
    __shared__ float sb[WW][DHEAD + 1];
    __shared__ float sd[WW][DHEAD];
    __shared__ float se[WW][DHEAD];
    __shared__ float pm_s[WIN][WW];
    __shared__ float pl_s[WIN][WW];

    const int tid = threadIdx.x;
    const size_t rowbase = ((size_t)b * T_SEQ) * NABCDE;
    const int hd = h * DHEAD;

    {
        int i  = tid >> 4;
        int d4 = (tid & 15) << 2;
        float4 v = *reinterpret_cast<const float4*>(
            &abcde[rowbase + (size_t)(n * WIN + i) * NABCDE + 2 * DMODEL + hd + d4]);
        sc[i][d4 + 0] = v.x; sc[i][d4 + 1] = v.y;
        sc[i][d4 + 2] = v.z; sc[i][d4 + 3] = v.w;
    }
#pragma unroll
    for (int r = 0; r < 2; ++r) {
        int f  = tid + r * 256;
        int m  = f >> 4;
        int d4 = (f & 15) << 2;
        int t  = n * WIN - WIN + m;
        float4 va = make_float4(0.f, 0.f, 0.f, 0.f), vb = va, vd = va, ve = va;
        if (t >= 0) {
            size_t base = rowbase + (size_t)t * NABCDE + hd + d4;
            va = *reinterpret_cast<const float4*>(&abcde[base + 0 * DMODEL]);
            vb = *reinterpret_cast<const float4*>(&abcde[base + 1 * DMODEL]);
            vd = *reinterpret_cast<const float4*>(&abcde[base + 3 * DMODEL]);
            ve = *reinterpret_cast<const float4*>(&abcde[base + 4 * DMODEL]);
        }
        sa[m][d4 + 0] = va.x; sa[m][d4 + 1] = va.y; sa[m][d4 + 2] = va.z; sa[m][d4 + 3] = va.w;
        sb[m][d4 + 0] = vb.x; sb[m][d4 + 1] = vb.y; sb[m][d4 + 2] = vb.z; sb[m][d4 + 3] = vb.w;
        *reinterpret_cast<float4*>(&sd[m][d4]) = vd;
        *reinterpret_cast<float4*>(&se[m][d4]) = ve;
    }
    __syncthreads();

    const int g  = tid >> 6;
    const int s  = tid & 63;
    const int m0 = (s & 7) << 2;
    const int l0 = (s >> 3) << 2;

    float p[4][4][4];
#pragma unroll
    for (int ii = 0; ii < 4; ++ii)
#pragma unroll
        for (int mi = 0; mi < 4; ++mi)
#pragma unroll
            for (int li = 0; li < 4; ++li) p[ii][mi][li] = 0.f;

#pragma unroll 4
    for (int d = 0; d < DHEAD; ++d) {
        float cv[4], av[4], bvv[4];
#pragma unroll
        for (int ii = 0; ii < 4; ++ii) cv[ii] = sc[g * 4 + ii][d];
#pragma unroll
        for (int mi = 0; mi < 4; ++mi) av[mi] = sa[m0 + mi][d];
#pragma unroll
        for (int li = 0; li < 4; ++li) bvv[li] = sb[l0 + li][d];
#pragma unroll
        for (int mi = 0; mi < 4; ++mi)
#pragma unroll
            for (int li = 0; li < 4; ++li) {
                float ab = av[mi] * bvv[li];
#pragma unroll
                for (int ii = 0; ii < 4; ++ii)
                    p[ii][mi][li] = fmaf(cv[ii], ab, p[ii][mi][li]);
            }
    }

    const int nbase = n * WIN;
#pragma unroll
    for (int ii = 0; ii < 4; ++ii) {
        int tq = nbase + g * 4 + ii;
#pragma unroll
        for (int mi = 0; mi < 4; ++mi) {
            int m = m0 + mi;
            int bbm = (n == 0 && m < WIN) ? 0 : (nbase - WIN + m);
#pragma unroll
            for (int li = 0; li < 4; ++li) {
                int l = l0 + li;
                int bbl = (n == 0 && l < WIN) ? 0 : (nbase - WIN + l);
                float v = p[ii][mi][li];
                bool keep = (tq >= bbl) && (bbl > bbm);
                if (!keep) v = IGNORE_V;
                if (v == 0.0f) v = IGNORE_V;
                p[ii][mi][li] = v * (1.0f / 64.0f);
            }
        }
    }

#pragma unroll
    for (int ii = 0; ii < 4; ++ii) {
        float mx = -3.4e38f;
#pragma unroll
        for (int mi = 0; mi < 4; ++mi)
#pragma unroll
            for (int li = 0; li < 4; ++li) mx = fmaxf(mx, p[ii][mi][li]);
#pragma unroll
        for (int off = 1; off < 64; off <<= 1)
            mx = fmaxf(mx, __shfl_xor(mx, off, 64));
        float sum = 0.f;
#pragma unroll
        for (int mi = 0; mi < 4; ++mi)
#pragma unroll
            for (int li = 0; li < 4; ++li) {
                float e = __expf(p[ii][mi][li] - mx);
                p[ii][mi][li] = e;
                sum += e;
            }
#pragma unroll
        for (int off = 1; off < 64; off <<= 1)
            sum += __shfl_xor(sum, off, 64);
        float inv = 1.0f / sum;
#pragma unroll
        for (int mi = 0; mi < 4; ++mi)
#pragma unroll
            for (int li = 0; li < 4; ++li) p[ii][mi][li] *= inv;
    }

#pragma unroll
    for (int ii = 0; ii < 4; ++ii) {
        int i = g * 4 + ii;
#pragma unroll
        for (int mi = 0; mi < 4; ++mi) {
            float pm = p[ii][mi][0] + p[ii][mi][1] + p[ii][mi][2] + p[ii][mi][3];
            pm += __shfl_xor(pm, 8, 64);
            pm += __shfl_xor(pm, 16, 64);
            pm += __shfl_xor(pm, 32, 64);
            if ((s >> 3) == 0) pm_s[i][m0 + mi] = pm;
        }
#pragma unroll
        for (int li = 0; li < 4; ++li) {
            float pl = p[ii][0][li] + p[ii][1][li] + p[ii][2][li] + p[ii][3][li];
            pl += __shfl_xor(pl, 1, 64);
            pl += __shfl_xor(pl, 2, 64);
            pl += __shfl_xor(pl, 4, 64);
            if ((s & 7) == 0) pl_s[i][l0 + li] = pl;
        }
    }
    __syncthreads();

    {
        int i  = tid >> 4;
        int d0 = (tid & 15) << 2;
        float4 acc = make_float4(0.f, 0.f, 0.f, 0.f);
#pragma unroll 8
        for (int m = 0; m < WW; ++m) {
            float pmv = pm_s[i][m];
            float4 dv = *reinterpret_cast<const float4*>(&sd[m][d0]);
            acc.x = fmaf(pmv, dv.x, acc.x);
            acc.y = fmaf(pmv, dv.y, acc.y);
            acc.z = fmaf(pmv, dv.z, acc.z);
            acc.w = fmaf(pmv, dv.w, acc.w);
            float plv = pl_s[i][m];
            float4 ev = *reinterpret_cast<const float4*>(&se[m][d0]);
            acc.x = fmaf(plv, ev.x, acc.x);
            acc.y = fmaf(plv, ev.y, acc.y);
            acc.z = fmaf(plv, ev.z, acc.z);
            acc.w = fmaf(plv, ev.w, acc.w);
        }
        size_t zoff = ((size_t)b * T_SEQ + n * WIN + i) * (NHEADS * DHEAD) + hd + d0;
        union { short s4[4]; uint2 u; } o;
        o.s4[0] = f2bf(acc.x); o.s4[1] = f2bf(acc.y);
        o.s4[2] = f2bf(acc.z); o.s4[3] = f2bf(acc.w);
        *reinterpret_cast<uint2*>(&z[zoff]) = o.u;
    }
}

// ---------------------------------------------------------------------------
extern "C" void kernel_launch(void* const* d_in, const int* in_sizes, int n_in,
                              void* d_out, int out_size, void* d_ws, size_t ws_size,
                              hipStream_t stream) {
    const float* x        = (const float*)d_in[0];
    const float* W_abcde  = (const float*)d_in[1];
    const float* b_abcde  = (const float*)d_in[2];
    const float* W_O      = (const float*)d_in[3];
    const float* b_O      = (const float*)d_in[4];
    float* out = (float*)d_out;

    char* ws = (char*)d_ws;
    float* abcde = (float*)ws;                               // 4096x3840 fp32 (62.9 MB)
    short* xb    = (short*)(ws + (size_t)62914560);          // 4096x768 bf16 (6.3 MB), reused as zb
    short* Wt    = (short*)(ws + (size_t)62914560 + 6291456);// 3840x768 bf16 (5.9 MB), reused as WOt
    short* zb    = xb;
    short* WOt   = Wt;

    const int M = 2 * T_SEQ;  // 4096

    // cast x -> bf16 (same layout)
    cast_bf16_kernel<<<dim3((M * DMODEL / 8 + 255) / 256), dim3(256), 0, stream>>>(
        x, xb, M * DMODEL);
    // transpose-cast W_abcde [768][3840] -> Wt [3840][768]
    transpose_cast_kernel<<<dim3(NABCDE / 32, DMODEL / 32), dim3(256), 0, stream>>>(
        W_abcde, Wt, DMODEL, NABCDE);

    // GEMM1: abcde = xb @ Wt^T + b_abcde
    gemm_bf16_mfma<<<dim3(NABCDE / 128, M / 128), dim3(256), 0, stream>>>(
        xb, Wt, b_abcde, abcde, M, NABCDE, DMODEL);

    // windowed trittention -> zb (bf16)
    attn_kernel<<<dim3(2 * NHEADS * NWIN), dim3(256), 0, stream>>>(abcde, zb);

    // transpose-cast W_O [768][768] -> WOt [768][768] (after GEMM1 freed Wt)
    transpose_cast_kernel<<<dim3(DMODEL / 32, DMODEL / 32), dim3(256), 0, stream>>>(
        W_O, WOt, DMODEL, DMODEL);

    // GEMM2: out = zb @ WOt^T + b_O
    gemm_bf16_mfma<<<dim3(DMODEL / 128, M / 128), dim3(256), 0, stream>>>(
        zb, WOt, b_O, out, M, DMODEL, DMODEL);
}

// Round 3
// 226.588 us; speedup vs baseline: 2.5609x; 1.1549x over previous
//
#include <hip/hip_runtime.h>

#define T_SEQ   2048
#define NHEADS  12
#define DHEAD   64
#define WIN     16
#define WW      32
#define NWIN    128
#define DMODEL  768
#define NABCDE  3840
#define IGNORE_V (-1.0e6f)
#define PAD_K   72          // bf16 LDS row stride (144 B): 2-way frag reads

typedef float f32x4 __attribute__((ext_vector_type(4)));
typedef short bf16x8 __attribute__((ext_vector_type(8)));

__device__ __forceinline__ short f2bf(float f) {
    unsigned u = __float_as_uint(f);
    unsigned r = (u + 0x7FFF + ((u >> 16) & 1)) >> 16;   // RNE
    return (short)r;
}
__device__ __forceinline__ float bf2f(short s) {
    return __uint_as_float(((unsigned)(unsigned short)s) << 16);
}

__device__ __forceinline__ void gload_lds16(const short* g, short* l) {
    __builtin_amdgcn_global_load_lds(
        (const __attribute__((address_space(1))) void*)g,
        (__attribute__((address_space(3))) void*)l,
        16, 0, 0);
}

// elementwise bf16 product (truncating round) for MFMA A-frag construction
__device__ __forceinline__ bf16x8 bmul8(bf16x8 x, bf16x8 y) {
    bf16x8 r;
#pragma unroll
    for (int j = 0; j < 8; ++j) {
        float fx = bf2f(x[j]);
        float fy = bf2f(y[j]);
        r[j] = (short)(__float_as_uint(fx * fy) >> 16);
    }
    return r;
}

// ---------------------------------------------------------------------------
// cast fp32 -> bf16, same layout. 8 elements/thread.
// ---------------------------------------------------------------------------
__global__ __launch_bounds__(256) void cast_bf16_kernel(
    const float* __restrict__ in, short* __restrict__ out, int n)
{
    int i = (blockIdx.x * 256 + threadIdx.x) * 8;
    if (i >= n) return;
    float4 a = *reinterpret_cast<const float4*>(&in[i]);
    float4 b = *reinterpret_cast<const float4*>(&in[i + 4]);
    union { short s[8]; uint4 u; } r;
    r.s[0] = f2bf(a.x); r.s[1] = f2bf(a.y); r.s[2] = f2bf(a.z); r.s[3] = f2bf(a.w);
    r.s[4] = f2bf(b.x); r.s[5] = f2bf(b.y); r.s[6] = f2bf(b.z); r.s[7] = f2bf(b.w);
    *reinterpret_cast<uint4*>(&out[i]) = r.u;
}

// ---------------------------------------------------------------------------
// transpose + cast: W[K][N] fp32 -> Wt[N][K] bf16.  32x32 LDS tile.
// ---------------------------------------------------------------------------
__global__ __launch_bounds__(256) void transpose_cast_kernel(
    const float* __restrict__ W, short* __restrict__ Wt, int K, int N)
{
    __shared__ float tile[32][33];
    const int bx = blockIdx.x * 32;
    const int by = blockIdx.y * 32;
    const int tx = threadIdx.x & 31, ty = threadIdx.x >> 5;
#pragma unroll
    for (int r = 0; r < 32; r += 8)
        tile[ty + r][tx] = W[(size_t)(by + ty + r) * N + bx + tx];
    __syncthreads();
#pragma unroll
    for (int r = 0; r < 32; r += 8)
        Wt[(size_t)(bx + ty + r) * K + by + tx] = f2bf(tile[tx][ty + r]);
}

// ---------------------------------------------------------------------------
// bf16 MFMA GEMM: C[M,N] = A[M,K] @ Bt[N,K]^T + bias[N]
// Output fp32 (BF16OUT=false) or bf16 (BF16OUT=true).
// ---------------------------------------------------------------------------
template <bool BF16OUT>
__global__ __launch_bounds__(256) void gemm_bf16_mfma(
    const short* __restrict__ A, const short* __restrict__ Bt,
    const float* __restrict__ bias, void* __restrict__ Cv,
    int M, int N, int K)
{
    __shared__ short As[128 * 32];
    __shared__ short Bs[128 * 32];

    const int tid  = threadIdx.x;
    const int wave = tid >> 6;
    const int lane = tid & 63;
    const int bm = blockIdx.y * 128;
    const int bn = blockIdx.x * 128;

    const int st_row = lane >> 2;
    const int st_col = (lane & 3) * 8;
    const int fr_m = lane & 15;
    const int fr_k = (lane >> 4) * 8;
    const int wm = (wave >> 1) * 64;
    const int wn = (wave & 1) * 64;

    f32x4 acc[4][4];
#pragma unroll
    for (int mi = 0; mi < 4; ++mi)
#pragma unroll
        for (int ni = 0; ni < 4; ++ni) acc[mi][ni] = (f32x4){0.f, 0.f, 0.f, 0.f};

    const short* Abase0 = A  + (size_t)(bm + wave * 32 + st_row)      * K + st_col;
    const short* Abase1 = A  + (size_t)(bm + wave * 32 + 16 + st_row) * K + st_col;
    const short* Bbase0 = Bt + (size_t)(bn + wave * 32 + st_row)      * K + st_col;
    const short* Bbase1 = Bt + (size_t)(bn + wave * 32 + 16 + st_row) * K + st_col;
    short* AL0 = &As[(wave * 32)      * 32];
    short* AL1 = &As[(wave * 32 + 16) * 32];
    short* BL0 = &Bs[(wave * 32)      * 32];
    short* BL1 = &Bs[(wave * 32 + 16) * 32];

    for (int k0 = 0; k0 < K; k0 += 32) {
        gload_lds16(Abase0 + k0, AL0);
        gload_lds16(Abase1 + k0, AL1);
        gload_lds16(Bbase0 + k0, BL0);
        gload_lds16(Bbase1 + k0, BL1);
        __syncthreads();

        bf16x8 af[4], bf[4];
#pragma unroll
        for (int mi = 0; mi < 4; ++mi)
            af[mi] = *reinterpret_cast<const bf16x8*>(
                &As[(wm + mi * 16 + fr_m) * 32 + fr_k]);
#pragma unroll
        for (int ni = 0; ni < 4; ++ni)
            bf[ni] = *reinterpret_cast<const bf16x8*>(
                &Bs[(wn + ni * 16 + fr_m) * 32 + fr_k]);
#pragma unroll
        for (int mi = 0; mi < 4; ++mi)
#pragma unroll
            for (int ni = 0; ni < 4; ++ni)
                acc[mi][ni] = __builtin_amdgcn_mfma_f32_16x16x32_bf16(
                    af[mi], bf[ni], acc[mi][ni], 0, 0, 0);
        __syncthreads();
    }

    float bv[4];
#pragma unroll
    for (int ni = 0; ni < 4; ++ni)
        bv[ni] = bias[bn + wn + ni * 16 + (lane & 15)];
#pragma unroll
    for (int mi = 0; mi < 4; ++mi) {
        int rbase = bm + wm + mi * 16 + (lane >> 4) * 4;
#pragma unroll
        for (int r = 0; r < 4; ++r) {
            size_t off = (size_t)(rbase + r) * N + bn + wn + (lane & 15);
#pragma unroll
            for (int ni = 0; ni < 4; ++ni) {
                float val = acc[mi][ni][r] + bv[ni];
                if (BF16OUT) ((short*)Cv)[off + ni * 16] = f2bf(val);
                else         ((float*)Cv)[off + ni * 16] = val;
            }
        }
    }
}

// ---------------------------------------------------------------------------
// Windowed trittention with MFMA scores. One block per (bh, window).
// Wave w owns m in [w*8, w*8+8). scores[i,m,l] = sum_d (c[i,d]a[m,d]) b[l,d]
// as 16x16x32 MFMAs with register-built A-frags.
// C-layout: i = (lane>>4)*4+reg, l = lhalf*16 + (lane&15).
// ---------------------------------------------------------------------------
__global__ __launch_bounds__(256) void attn_kernel(
    const short* __restrict__ abcde, short* __restrict__ z)
{
    const int blk = blockIdx.x;
    const int n  = blk & (NWIN - 1);
    const int bh = blk >> 7;
    const int b  = bh / NHEADS;
    const int h  = bh % NHEADS;

    __shared__ short sc[WIN * PAD_K];
    __shared__ short sa[WW * PAD_K];
    __shared__ short sb[WW * PAD_K];
    __shared__ short sd[WW * DHEAD];
    __shared__ short se[WW * DHEAD];
    __shared__ float red[2][4][WIN];          // [max/sum][wave][i]
    __shared__ float pm_s[WIN][WW];           // inv-scaled row-marginal
    __shared__ float pl_part[4][WIN][WW];     // per-wave col-marginal

    const int tid = threadIdx.x;
    const size_t rowbase = ((size_t)b * T_SEQ) * NABCDE;
    const int hd = h * DHEAD;

    // ---- staging (bf16, 16B chunks)
    if (tid < 128) {
        int row = tid >> 3, ch = (tid & 7) * 8;
        *reinterpret_cast<uint4*>(&sc[row * PAD_K + ch]) =
            *reinterpret_cast<const uint4*>(
                &abcde[rowbase + (size_t)(n * WIN + row) * NABCDE + 2 * DMODEL + hd + ch]);
    }
    {
        int row = tid >> 3, ch = (tid & 7) * 8;
        int t = n * WIN - WIN + row;
        uint4 va = {0u, 0u, 0u, 0u}, vb = va, vd = va, ve = va;
        if (t >= 0) {
            size_t base = rowbase + (size_t)t * NABCDE + hd + ch;
            va = *reinterpret_cast<const uint4*>(&abcde[base + 0 * DMODEL]);
            vb = *reinterpret_cast<const uint4*>(&abcde[base + 1 * DMODEL]);
            vd = *reinterpret_cast<const uint4*>(&abcde[base + 3 * DMODEL]);
            ve = *reinterpret_cast<const uint4*>(&abcde[base + 4 * DMODEL]);
        }
        *reinterpret_cast<uint4*>(&sa[row * PAD_K + ch]) = va;
        *reinterpret_cast<uint4*>(&sb[row * PAD_K + ch]) = vb;
        *reinterpret_cast<uint4*>(&sd[row * DHEAD + ch]) = vd;
        *reinterpret_cast<uint4*>(&se[row * DHEAD + ch]) = ve;
    }
    __syncthreads();

    const int wv = tid >> 6;
    const int lane = tid & 63;
    const int lc = lane & 15;        // A-row (i) / B-row (l) for frag loads; col for C
    const int ko = lane >> 4;        // k-chunk selector; C row group

    // ---- fragments reused across all m
    bf16x8 cfrag[2], bfrag[2][2];
#pragma unroll
    for (int kt = 0; kt < 2; ++kt) {
        cfrag[kt]    = *reinterpret_cast<const bf16x8*>(&sc[lc * PAD_K + kt * 32 + ko * 8]);
        bfrag[0][kt] = *reinterpret_cast<const bf16x8*>(&sb[lc * PAD_K + kt * 32 + ko * 8]);
        bfrag[1][kt] = *reinterpret_cast<const bf16x8*>(&sb[(16 + lc) * PAD_K + kt * 32 + ko * 8]);
    }

    f32x4 acc[8][2];
#pragma unroll
    for (int mi = 0; mi < 8; ++mi) {
        acc[mi][0] = (f32x4){0.f, 0.f, 0.f, 0.f};
        acc[mi][1] = (f32x4){0.f, 0.f, 0.f, 0.f};
    }

#pragma unroll
    for (int mi = 0; mi < 8; ++mi) {
        int m = wv * 8 + mi;
#pragma unroll
        for (int kt = 0; kt < 2; ++kt) {
            bf16x8 ar = *reinterpret_cast<const bf16x8*>(&sa[m * PAD_K + kt * 32 + ko * 8]);
            bf16x8 af = bmul8(cfrag[kt], ar);
            acc[mi][0] = __builtin_amdgcn_mfma_f32_16x16x32_bf16(af, bfrag[0][kt], acc[mi][0], 0, 0, 0);
            acc[mi][1] = __builtin_amdgcn_mfma_f32_16x16x32_bf16(af, bfrag[1][kt], acc[mi][1], 0, 0, 0);
        }
    }

    // ---- mask + scale, per-lane max
    const int nbase = n * WIN;
    int bbl[2];
#pragma unroll
    for (int h2 = 0; h2 < 2; ++h2) {
        int l = h2 * 16 + lc;
        bbl[h2] = (n == 0 && l < WIN) ? 0 : (nbase - WIN + l);
    }
    float mx[4] = {-3.4e38f, -3.4e38f, -3.4e38f, -3.4e38f};
#pragma unroll
    for (int mi = 0; mi < 8; ++mi) {
        int m = wv * 8 + mi;
        int bbm = (n == 0 && m < WIN) ? 0 : (nbase - WIN + m);
#pragma unroll
        for (int h2 = 0; h2 < 2; ++h2) {
#pragma unroll
            for (int reg = 0; reg < 4; ++reg) {
                int tq = nbase + ko * 4 + reg;
                float v = acc[mi][h2][reg];
                bool keep = (tq >= bbl[h2]) && (bbl[h2] > bbm);
                if (!keep || v == 0.0f) v = IGNORE_V;
                v *= (1.0f / 64.0f);
                acc[mi][h2][reg] = v;
                mx[reg] = fmaxf(mx[reg], v);
            }
        }
    }
#pragma unroll
    for (int reg = 0; reg < 4; ++reg) {
        mx[reg] = fmaxf(mx[reg], __shfl_xor(mx[reg], 1, 64));
        mx[reg] = fmaxf(mx[reg], __shfl_xor(mx[reg], 2, 64));
        mx[reg] = fmaxf(mx[reg], __shfl_xor(mx[reg], 4, 64));
        mx[reg] = fmaxf(mx[reg], __shfl_xor(mx[reg], 8, 64));
    }
    if (lc == 0) {
#pragma unroll
        for (int reg = 0; reg < 4; ++reg) red[0][wv][ko * 4 + reg] = mx[reg];
    }
    __syncthreads();

    float gmax[4];
#pragma unroll
    for (int reg = 0; reg < 4; ++reg) {
        int i = ko * 4 + reg;
        gmax[reg] = fmaxf(fmaxf(red[0][0][i], red[0][1][i]),
                          fmaxf(red[0][2][i], red[0][3][i]));
    }

    // ---- exp + per-lane sum
    float sm[4] = {0.f, 0.f, 0.f, 0.f};
#pragma unroll
    for (int mi = 0; mi < 8; ++mi)
#pragma unroll
        for (int h2 = 0; h2 < 2; ++h2)
#pragma unroll
            for (int reg = 0; reg < 4; ++reg) {
                float e = __expf(acc[mi][h2][reg] - gmax[reg]);
                acc[mi][h2][reg] = e;
                sm[reg] += e;
            }
#pragma unroll
    for (int reg = 0; reg < 4; ++reg) {
        sm[reg] += __shfl_xor(sm[reg], 1, 64);
        sm[reg] += __shfl_xor(sm[reg], 2, 64);
        sm[reg] += __shfl_xor(sm[reg], 4, 64);
        sm[reg] += __shfl_xor(sm[reg], 8, 64);
    }
    if (lc == 0) {
#pragma unroll
        for (int reg = 0; reg < 4; ++reg) red[1][wv][ko * 4 + reg] = sm[reg];
    }
    __syncthreads();

    float inv[4];
#pragma unroll
    for (int reg = 0; reg < 4; ++reg) {
        int i = ko * 4 + reg;
        inv[reg] = 1.0f / (red[1][0][i] + red[1][1][i] + red[1][2][i] + red[1][3][i]);
    }

    // ---- marginals (inv-scaled): pl (in-lane over m), pm (butterfly over l)
#pragma unroll
    for (int h2 = 0; h2 < 2; ++h2)
#pragma unroll
        for (int reg = 0; reg < 4; ++reg) {
            float pl = 0.f;
#pragma unroll
            for (int mi = 0; mi < 8; ++mi) pl += acc[mi][h2][reg];
            pl_part[wv][ko * 4 + reg][h2 * 16 + lc] = pl * inv[reg];
        }
#pragma unroll
    for (int mi = 0; mi < 8; ++mi)
#pragma unroll
        for (int reg = 0; reg < 4; ++reg) {
            float pm = acc[mi][0][reg] + acc[mi][1][reg];
            pm += __shfl_xor(pm, 1, 64);
            pm += __shfl_xor(pm, 2, 64);
            pm += __shfl_xor(pm, 4, 64);
            pm += __shfl_xor(pm, 8, 64);
            if (lc == 0) pm_s[ko * 4 + reg][wv * 8 + mi] = pm * inv[reg];
        }
    __syncthreads();

    // ---- z[i,d] = sum_m pm[i,m]*d_l[m,d] + sum_l pl[i,l]*e_l[l,d]
    {
        int i  = tid >> 4;
        int d0 = (tid & 15) * 4;
        float4 acc4 = make_float4(0.f, 0.f, 0.f, 0.f);
#pragma unroll 8
        for (int m = 0; m < WW; ++m) {
            float pmv = pm_s[i][m];
            float plv = pl_part[0][i][m] + pl_part[1][i][m] +
                        pl_part[2][i][m] + pl_part[3][i][m];
            uint2 du = *reinterpret_cast<const uint2*>(&sd[m * DHEAD + d0]);
            uint2 eu = *reinterpret_cast<const uint2*>(&se[m * DHEAD + d0]);
            const short* dp = (const short*)&du;
            const short* ep = (const short*)&eu;
            acc4.x = fmaf(pmv, bf2f(dp[0]), fmaf(plv, bf2f(ep[0]), acc4.x));
            acc4.y = fmaf(pmv, bf2f(dp[1]), fmaf(plv, bf2f(ep[1]), acc4.y));
            acc4.z = fmaf(pmv, bf2f(dp[2]), fmaf(plv, bf2f(ep[2]), acc4.z));
            acc4.w = fmaf(pmv, bf2f(dp[3]), fmaf(plv, bf2f(ep[3]), acc4.w));
        }
        size_t zoff = ((size_t)b * T_SEQ + n * WIN + i) * (NHEADS * DHEAD) + hd + d0;
        union { short s4[4]; uint2 u; } o;
        o.s4[0] = f2bf(acc4.x); o.s4[1] = f2bf(acc4.y);
        o.s4[2] = f2bf(acc4.z); o.s4[3] = f2bf(acc4.w);
        *reinterpret_cast<uint2*>(&z[zoff]) = o.u;
    }
}

// ---------------------------------------------------------------------------
extern "C" void kernel_launch(void* const* d_in, const int* in_sizes, int n_in,
                              void* d_out, int out_size, void* d_ws, size_t ws_size,
                              hipStream_t stream) {
    const float* x        = (const float*)d_in[0];
    const float* W_abcde  = (const float*)d_in[1];
    const float* b_abcde  = (const float*)d_in[2];
    const float* W_O      = (const float*)d_in[3];
    const float* b_O      = (const float*)d_in[4];
    float* out = (float*)d_out;

    char* ws = (char*)d_ws;
    short* abcde = (short*)ws;                                 // 4096x3840 bf16 (31.5 MB)
    short* xb    = (short*)(ws + (size_t)31457280);            // 4096x768 bf16, reused as zb
    short* Wt    = (short*)(ws + (size_t)31457280 + 6291456);  // 3840x768 bf16, reused as WOt
    short* zb    = xb;
    short* WOt   = Wt;

    const int M = 2 * T_SEQ;  // 4096

    cast_bf16_kernel<<<dim3((M * DMODEL / 8 + 255) / 256), dim3(256), 0, stream>>>(
        x, xb, M * DMODEL);
    transpose_cast_kernel<<<dim3(NABCDE / 32, DMODEL / 32), dim3(256), 0, stream>>>(
        W_abcde, Wt, DMODEL, NABCDE);

    // GEMM1 -> bf16 abcde
    gemm_bf16_mfma<true><<<dim3(NABCDE / 128, M / 128), dim3(256), 0, stream>>>(
        xb, Wt, b_abcde, (void*)abcde, M, NABCDE, DMODEL);

    // windowed trittention -> zb (bf16)
    attn_kernel<<<dim3(2 * NHEADS * NWIN), dim3(256), 0, stream>>>(abcde, zb);

    transpose_cast_kernel<<<dim3(DMODEL / 32, DMODEL / 32), dim3(256), 0, stream>>>(
        W_O, WOt, DMODEL, DMODEL);

    // GEMM2 -> fp32 out
    gemm_bf16_mfma<false><<<dim3(DMODEL / 128, M / 128), dim3(256), 0, stream>>>(
        zb, WOt, b_O, (void*)out, M, DMODEL, DMODEL);
}